// Round 5
// baseline (141.794 us; speedup 1.0000x reference)
//
#include <hip/hip_runtime.h>

// x[32,64,224,224] f32 -> BN(affine)+ReLU -> 1x1 conv(64->32) -> avgpool 2x2 s2
//   == relu-affine(+0.25 folded) -> pool -> 32x64 matvec (conv commutes w/ pool).
// Memory-bound stream: 411MB read + 51MB write ~= 73.5us at 6.3 TB/s.
// R5: back to R1's barrier-free structure (LDS lockstep pipelines R3/R4 were
//   3.3 TB/s vs R1's 4.4). Role-split pixel-pairs:
//   thread = (pair, role=wave&1); each thread float4-loads the 2x4 window
//   (64 distinct lanes -> 1KB contiguous per wave-load, 2x R1's granule),
//   computes BN+pool for both pixels, accumulates 16 of 32 outputs
//   -> acc stays 32 VGPR (R2's occupancy collapse avoided).
//   Role wave-uniform -> conv_w via scalar loads (SGPR fma operands).
//   Role-pair waves re-read the same lines -> L1/L2 dedup keeps HBM at 411MB.

#define EPS_BN 1e-5f

constexpr int N_   = 32;
constexpr int CIN  = 64;
constexpr int COUT = 32;
constexpr int H_   = 224;
constexpr int W_   = 224;
constexpr int H2   = 112;
constexpr int W2   = 112;
constexpr int PAIRS = N_ * H2 * (W2 / 2);   // 200704 pixel-pairs
constexpr int THREADS = 256;                // 4 waves: roles 0,1,0,1
constexpr int PAIRS_PB = 128;               // pairs per block (2 role-waves each)

__global__ __launch_bounds__(THREADS) void fused(
    const float* __restrict__ x,
    const float* __restrict__ conv_w,
    const float* __restrict__ gamma,
    const float* __restrict__ beta,
    const float* __restrict__ rmean,
    const float* __restrict__ rvar,
    float* __restrict__ out) {
  __shared__ float sb[2][CIN];   // folded BN scale/bias (x0.25 pool)

  const int tid  = threadIdx.x;
  if (tid < CIN) {
    float s = gamma[tid] * rsqrtf(rvar[tid] + EPS_BN);
    float b = beta[tid] - rmean[tid] * s;
    sb[0][tid] = 0.25f * s;      // 0.25*relu(s*x+b) == relu(.25s*x+.25b)
    sb[1][tid] = 0.25f * b;
  }
  __syncthreads();

  const int lane = tid & 63;
  const int wave = tid >> 6;                 // 0..3
  const int role = wave & 1;                 // wave-uniform -> SGPR weights
  const int pl   = lane + 64 * (wave >> 1);  // pair-local 0..127

  const int P  = blockIdx.x * PAIRS_PB + pl; // global pair id
  const int n  = P / (H2 * (W2 / 2));
  const int r  = P - n * (H2 * (W2 / 2));
  const int h2 = r / (W2 / 2);
  const int w4 = r - h2 * (W2 / 2);          // pooled cols 2*w4, 2*w4+1

  // 2x4 window base (x rows 2h2,2h2+1; cols 4*w4..4*w4+3), 16B aligned
  const float* __restrict__ px =
      x + ((size_t)n * CIN * H_ + (size_t)(2 * h2)) * W_ + (size_t)(4 * w4);
  const float* __restrict__ wrow = conv_w + (role * 16) * CIN;  // uniform

  float acc0[16], acc1[16];
#pragma unroll
  for (int o = 0; o < 16; ++o) { acc0[o] = 0.0f; acc1[o] = 0.0f; }

#pragma unroll
  for (int c = 0; c < CIN; ++c) {
    const float* p = px + (size_t)c * (H_ * W_);
    float4 r0 = *reinterpret_cast<const float4*>(p);
    float4 r1 = *reinterpret_cast<const float4*>(p + W_);
    float s  = sb[0][c];         // uniform addr -> LDS broadcast
    float bb = sb[1][c];
    float y0 = fmaxf(fmaf(r0.x, s, bb), 0.0f) + fmaxf(fmaf(r0.y, s, bb), 0.0f)
             + fmaxf(fmaf(r1.x, s, bb), 0.0f) + fmaxf(fmaf(r1.y, s, bb), 0.0f);
    float y1 = fmaxf(fmaf(r0.z, s, bb), 0.0f) + fmaxf(fmaf(r0.w, s, bb), 0.0f)
             + fmaxf(fmaf(r1.z, s, bb), 0.0f) + fmaxf(fmaf(r1.w, s, bb), 0.0f);
#pragma unroll
    for (int o = 0; o < 16; ++o) {
      float w = wrow[o * CIN + c];           // wave-uniform -> s_load
      acc0[o] = fmaf(w, y0, acc0[o]);
      acc1[o] = fmaf(w, y1, acc1[o]);
    }
  }

  // out[((n*32 + role*16 + o)*112 + h2)*112 + 2*w4], float2 per output
  float* __restrict__ po =
      out + ((size_t)(n * COUT + role * 16) * H2 + (size_t)h2) * W2 + (size_t)(2 * w4);
#pragma unroll
  for (int o = 0; o < 16; ++o) {
    float2 v = make_float2(acc0[o], acc1[o]);
    *reinterpret_cast<float2*>(po + (size_t)o * (H2 * W2)) = v;
  }
}

extern "C" void kernel_launch(void* const* d_in, const int* in_sizes, int n_in,
                              void* d_out, int out_size, void* d_ws, size_t ws_size,
                              hipStream_t stream) {
  const float* x      = (const float*)d_in[0];
  const float* conv_w = (const float*)d_in[1];
  const float* gamma  = (const float*)d_in[2];
  const float* beta   = (const float*)d_in[3];
  const float* rmean  = (const float*)d_in[4];
  const float* rvar   = (const float*)d_in[5];
  float* out = (float*)d_out;

  fused<<<PAIRS / PAIRS_PB * 2 / 2, THREADS, 0, stream>>>(  // 1568 blocks
      x, conv_w, gamma, beta, rmean, rvar, out);
}

// Round 6
// 94.260 us; speedup vs baseline: 1.5043x; 1.5043x over previous
//
#include <hip/hip_runtime.h>
#include <hip/hip_bf16.h>

// x[32,64,224,224] f32 -> BN(affine)+ReLU -> 1x1 conv(64->32) -> avgpool 2x2 s2
//   == relu-affine -> pool -> 32x64 matvec (conv commutes with pool).
// Memory-bound stream: 411MB read + 51MB write ~= 73.5us at 6.3 TB/s copy rate.
// Scoreboard: R1 (this structure, full unroll) 104.8us; LDS pipelines 138-142;
//   2pix/thread 162; role-split 142. -> iterate on R1.
// R6 theory: R1's full 64-ch unroll let the compiler hoist huge load clusters
//   -> VGPR ~150-200 -> 2-3 waves/SIMD (512 VGPR/SIMD budget, m69) -> latency
//   bound at 4.4 TB/s. Fix: #pragma unroll 4 caps landing zones -> ~80 VGPR
//   -> 5-6 waves/SIMD. Plus nontemporal stores (out never re-read).

#define EPS_BN 1e-5f

constexpr int N_   = 32;
constexpr int CIN  = 64;
constexpr int COUT = 32;
constexpr int H_   = 224;
constexpr int W_   = 224;
constexpr int H2   = 112;
constexpr int W2   = 112;
constexpr int PIX  = N_ * H2 * W2;       // 401408 pooled pixels
constexpr int BLK  = 256;

// d_ws layout (floats): [0..63]=scale, [64..127]=bias, [128..128+2048)=wT[c][o]
__global__ void prep_kernel(const float* __restrict__ conv_w,
                            const float* __restrict__ gamma,
                            const float* __restrict__ beta,
                            const float* __restrict__ rmean,
                            const float* __restrict__ rvar,
                            float* __restrict__ ws) {
    int c = threadIdx.x;            // 64 threads, one per input channel
    if (c < CIN) {
        float s = gamma[c] * rsqrtf(rvar[c] + EPS_BN);
        float b = beta[c] - rmean[c] * s;
        ws[c]        = 0.25f * s;   // fold 2x2-mean: 0.25*relu(sx+b)=relu(.25sx+.25b)
        ws[CIN + c]  = 0.25f * b;
        for (int o = 0; o < COUT; ++o)
            ws[2 * CIN + c * COUT + o] = conv_w[o * CIN + c];
    }
}

__global__ __launch_bounds__(BLK) void fused_kernel(const float* __restrict__ x,
                                                    const float* __restrict__ ws,
                                                    float* __restrict__ out) {
    const float* __restrict__ sc = ws;            // [64]
    const float* __restrict__ bi = ws + CIN;      // [64]
    const float* __restrict__ wT = ws + 2 * CIN;  // [64][32]

    int i = blockIdx.x * BLK + threadIdx.x;       // pooled pixel id
    int n  = i / (H2 * W2);
    int r  = i - n * (H2 * W2);
    int h2 = r / W2;
    int w2 = r - h2 * W2;

    // base of the 2x2 window for channel 0
    const float* __restrict__ px =
        x + ((size_t)n * CIN * H_ + (size_t)(2 * h2)) * W_ + (size_t)(2 * w2);

    float acc[COUT];
#pragma unroll
    for (int o = 0; o < COUT; ++o) acc[o] = 0.0f;

#pragma unroll 4   // cap load landing zones -> keep VGPR low -> 5-6 waves/SIMD
    for (int c = 0; c < CIN; ++c) {
        const float* p = px + (size_t)c * (H_ * W_);
        float2 r0 = *reinterpret_cast<const float2*>(p);
        float2 r1 = *reinterpret_cast<const float2*>(p + W_);
        float s = sc[c];   // uniform address -> s_load, broadcast
        float b = bi[c];
        float y = fmaxf(fmaf(r0.x, s, b), 0.0f)
                + fmaxf(fmaf(r0.y, s, b), 0.0f)
                + fmaxf(fmaf(r1.x, s, b), 0.0f)
                + fmaxf(fmaf(r1.y, s, b), 0.0f);
#pragma unroll
        for (int o = 0; o < COUT; ++o)
            acc[o] = fmaf(wT[c * COUT + o], y, acc[o]);  // wT uniform -> SGPR operand
    }

    // out[((n*COUT + o)*H2 + h2)*W2 + w2]; never re-read -> nontemporal
    float* __restrict__ po = out + ((size_t)n * COUT * H2 + (size_t)h2) * W2 + (size_t)w2;
#pragma unroll
    for (int o = 0; o < COUT; ++o)
        __builtin_nontemporal_store(acc[o], po + (size_t)o * (H2 * W2));
}

extern "C" void kernel_launch(void* const* d_in, const int* in_sizes, int n_in,
                              void* d_out, int out_size, void* d_ws, size_t ws_size,
                              hipStream_t stream) {
    const float* x      = (const float*)d_in[0];
    const float* conv_w = (const float*)d_in[1];
    const float* gamma  = (const float*)d_in[2];
    const float* beta   = (const float*)d_in[3];
    const float* rmean  = (const float*)d_in[4];
    const float* rvar   = (const float*)d_in[5];
    float* out = (float*)d_out;
    float* ws  = (float*)d_ws;

    prep_kernel<<<1, 64, 0, stream>>>(conv_w, gamma, beta, rmean, rvar, ws);
    fused_kernel<<<PIX / BLK, BLK, 0, stream>>>(x, ws, out);
}

// Round 7
// 87.391 us; speedup vs baseline: 1.6225x; 1.0786x over previous
//
#include <hip/hip_runtime.h>
#include <hip/hip_bf16.h>

// x[32,64,224,224] f32 -> BN(affine)+ReLU -> 1x1 conv(64->32) -> avgpool 2x2 s2
//   == relu-affine(0.25 folded) -> pool -> 32x64 matvec (conv commutes w/ pool).
// Memory-bound stream: 411MB read + 51MB write ~= 73.5us at 6.3 TB/s copy rate.
// Scoreboard: R1 full-unroll 104.8 | R6 unroll4+nt-store 94.3 | pipelines 138+.
// R7: unroll 8 (2x bytes in flight/wave) + __launch_bounds__(256,5) pins
//   VGPR<=102 so occupancy holds >=20 waves/CU + nontemporal x loads (zero
//   reuse -> evict-first, keep L2 for ws) + parallel prep (2048 thr).

#define EPS_BN 1e-5f

typedef float v2f __attribute__((ext_vector_type(2)));

constexpr int N_   = 32;
constexpr int CIN  = 64;
constexpr int COUT = 32;
constexpr int H_   = 224;
constexpr int W_   = 224;
constexpr int H2   = 112;
constexpr int W2   = 112;
constexpr int PIX  = N_ * H2 * W2;       // 401408 pooled pixels
constexpr int BLK  = 256;

// d_ws layout (floats): [0..63]=scale, [64..127]=bias, [128..128+2048)=wT[c][o]
__global__ void prep_kernel(const float* __restrict__ conv_w,
                            const float* __restrict__ gamma,
                            const float* __restrict__ beta,
                            const float* __restrict__ rmean,
                            const float* __restrict__ rvar,
                            float* __restrict__ ws) {
    int j = blockIdx.x * blockDim.x + threadIdx.x;   // 0..2047
    if (j < CIN * COUT) {
        int c = j >> 5, o = j & 31;                  // wT[c][o] = conv_w[o][c]
        ws[2 * CIN + j] = conv_w[o * CIN + c];
    }
    if (j < CIN) {
        float s = gamma[j] * rsqrtf(rvar[j] + EPS_BN);
        float b = beta[j] - rmean[j] * s;
        ws[j]       = 0.25f * s;   // fold 2x2-mean into BN affine
        ws[CIN + j] = 0.25f * b;
    }
}

__global__ __launch_bounds__(BLK, 5) void fused_kernel(const float* __restrict__ x,
                                                       const float* __restrict__ ws,
                                                       float* __restrict__ out) {
    const float* __restrict__ sc = ws;            // [64]
    const float* __restrict__ bi = ws + CIN;      // [64]
    const float* __restrict__ wT = ws + 2 * CIN;  // [64][32]

    int i = blockIdx.x * BLK + threadIdx.x;       // pooled pixel id
    int n  = i / (H2 * W2);
    int r  = i - n * (H2 * W2);
    int h2 = r / W2;
    int w2 = r - h2 * W2;

    // base of the 2x2 window for channel 0
    const float* __restrict__ px =
        x + ((size_t)n * CIN * H_ + (size_t)(2 * h2)) * W_ + (size_t)(2 * w2);

    float acc[COUT];
#pragma unroll
    for (int o = 0; o < COUT; ++o) acc[o] = 0.0f;

#pragma unroll 8   // 16 loads (~4KB/wave) in flight; VGPR capped by launch_bounds
    for (int c = 0; c < CIN; ++c) {
        const float* p = px + (size_t)c * (H_ * W_);
        v2f r0 = __builtin_nontemporal_load(reinterpret_cast<const v2f*>(p));
        v2f r1 = __builtin_nontemporal_load(reinterpret_cast<const v2f*>(p + W_));
        float s = sc[c];   // uniform address -> s_load, broadcast
        float b = bi[c];
        float y = fmaxf(fmaf(r0.x, s, b), 0.0f)
                + fmaxf(fmaf(r0.y, s, b), 0.0f)
                + fmaxf(fmaf(r1.x, s, b), 0.0f)
                + fmaxf(fmaf(r1.y, s, b), 0.0f);
#pragma unroll
        for (int o = 0; o < COUT; ++o)
            acc[o] = fmaf(wT[c * COUT + o], y, acc[o]);  // wT uniform -> SGPR operand
    }

    // out[((n*COUT + o)*H2 + h2)*W2 + w2]; never re-read -> nontemporal
    float* __restrict__ po = out + ((size_t)n * COUT * H2 + (size_t)h2) * W2 + (size_t)w2;
#pragma unroll
    for (int o = 0; o < COUT; ++o)
        __builtin_nontemporal_store(acc[o], po + (size_t)o * (H2 * W2));
}

extern "C" void kernel_launch(void* const* d_in, const int* in_sizes, int n_in,
                              void* d_out, int out_size, void* d_ws, size_t ws_size,
                              hipStream_t stream) {
    const float* x      = (const float*)d_in[0];
    const float* conv_w = (const float*)d_in[1];
    const float* gamma  = (const float*)d_in[2];
    const float* beta   = (const float*)d_in[3];
    const float* rmean  = (const float*)d_in[4];
    const float* rvar   = (const float*)d_in[5];
    float* out = (float*)d_out;
    float* ws  = (float*)d_ws;

    prep_kernel<<<(CIN * COUT + BLK - 1) / BLK, BLK, 0, stream>>>(
        conv_w, gamma, beta, rmean, rvar, ws);
    fused_kernel<<<PIX / BLK, BLK, 0, stream>>>(x, ws, out);
}